// Round 1
// baseline (8729.012 us; speedup 1.0000x reference)
//
#include <hip/hip_runtime.h>
#include <cmath>

typedef __bf16 bf16x8 __attribute__((ext_vector_type(8)));
typedef float  f32x4  __attribute__((ext_vector_type(4)));
typedef unsigned int u32;
typedef unsigned long long u64;
typedef u32 u32x4v __attribute__((ext_vector_type(4)));

#define T_STEPS 1024
#define I_DIM   256
#define H_DIM   512
#define B_TOT   64
#define NBT     4     // batch tiles
#define NCT     32    // column tiles
#define BT      16    // batches per tile
#define CT      16    // columns per gate per WG
#define WPB     (H_DIM / 2)        // LL words per batch row (2 bf16 per word)
#define LLSZ    (2 * NBT * BT * WPB)   // u64 words per LL buffer (both parities)

__device__ __forceinline__ f32x4 mfma16(bf16x8 a, bf16x8 b, f32x4 c) {
    return __builtin_amdgcn_mfma_f32_16x16x32_bf16(a, b, c, 0, 0, 0);
}

// two float4 registers -> bf16x8 A-fragment (pure VALU, no loads)
__device__ __forceinline__ bf16x8 cvt8r(float4 a, float4 b) {
    bf16x8 f;
    f[0] = (__bf16)a.x; f[1] = (__bf16)a.y; f[2] = (__bf16)a.z; f[3] = (__bf16)a.w;
    f[4] = (__bf16)b.x; f[5] = (__bf16)b.y; f[6] = (__bf16)b.z; f[7] = (__bf16)b.w;
    return f;
}

// relaxed agent-scope 8B atomics: the LL word = {lo32: 2x bf16 data | hi32: step tag}
__device__ __forceinline__ u64 ld_u64(const u64* p) {
    return __hip_atomic_load(p, __ATOMIC_RELAXED, __HIP_MEMORY_SCOPE_AGENT);
}
__device__ __forceinline__ void st_u64(u64* p, u64 v) {
    __hip_atomic_store(p, v, __ATOMIC_RELAXED, __HIP_MEMORY_SCOPE_AGENT);
}

// Poll 16 LL words (4 k-chunks x 4 words) until every lane sees all tags == tag.
// Data arrives in the same 8B loads as the tags -> single LLC trip per sync.
__device__ __forceinline__ void ll_poll16(const u64* b0, const u64* b1,
                                          const u64* b2, const u64* b3,
                                          u32 tag, u64* wrd) {
    for (int g = 0; g < (1 << 20); ++g) {
        #pragma unroll
        for (int k = 0; k < 4; ++k) {
            wrd[0  + k] = ld_u64(b0 + k);
            wrd[4  + k] = ld_u64(b1 + k);
            wrd[8  + k] = ld_u64(b2 + k);
            wrd[12 + k] = ld_u64(b3 + k);
        }
        bool ok = true;
        #pragma unroll
        for (int x = 0; x < 16; ++x) ok &= ((u32)(wrd[x] >> 32) == tag);
        if (__ballot(ok) == ~0ull) break;
    }
}

// 4 LL words -> bf16x8 A-fragment (low 32 bits of each word = 2 bf16 cols)
__device__ __forceinline__ bf16x8 frag_of(const u64* wrd) {
    u32x4v d;
    d.x = (u32)wrd[0]; d.y = (u32)wrd[1]; d.z = (u32)wrd[2]; d.w = (u32)wrd[3];
    return __builtin_bit_cast(bf16x8, d);
}

// Persistent GRU. Grid: 128 WGs = 4 batch-tiles x 32 column-tiles, 256 thr (4 waves).
// Wave w owns K-steps kk = w + 4*s (s=0..5) of K=768 ([x(256); h(512)]).
// h and r*h are exchanged via LL words; each wave waits only on its own k-range.
__global__ __launch_bounds__(256, 1) void gru_persist(
    const float* __restrict__ xs,
    const float* __restrict__ Wz, const float* __restrict__ bz,
    const float* __restrict__ Wr, const float* __restrict__ br,
    const float* __restrict__ Wh, const float* __restrict__ bh,
    float* __restrict__ out,
    u64* hll, u64* rhll)
{
    const int bid  = blockIdx.x;
    const int i    = bid & (NBT - 1);
    const int j    = bid >> 2;
    const int tid  = threadIdx.x;
    const int w    = tid >> 6;
    const int lane = tid & 63;
    const int q    = lane >> 4;
    const int ln   = lane & 15;
    const int cb   = j * CT;

    __shared__ float red1[2][4][16][17];
    __shared__ float red2[4][16][17];

    // ---- stationary weight B-fragments: B[k=q*8+jj][n=ln] per K-step ----
    bf16x8 BZ[6], BR[6], BH[6];
    #pragma unroll
    for (int s = 0; s < 6; ++s) {
        int kk = w + 4 * s;
        int krow = kk * 32 + q * 8;
        bf16x8 fz, fr, fh;
        #pragma unroll
        for (int jj = 0; jj < 8; ++jj) {
            int off = (krow + jj) * H_DIM + cb + ln;
            fz[jj] = (__bf16)Wz[off];
            fr[jj] = (__bf16)Wr[off];
            fh[jj] = (__bf16)Wh[off];
        }
        BZ[s] = fz; BR[s] = fr; BH[s] = fh;
    }

    const int m = tid >> 4;       // epilogue thread -> (batch m, col c)
    const int c = tid & 15;
    const float bzc = bz[cb + c], brc = br[cb + c], bhc = bh[cb + c];
    float hprev = 0.0f;

    const float* xrow = xs + (size_t)(i * BT + ln) * T_STEPS * I_DIM;

    // consumer LL base offsets within this wave's k-range: kk-8 = w + {0,4,8,12}
    const int widx = q * 4;       // word offset within a 32-col k-chunk (16 words)

    // x fragments for current step held in registers (loaded one step ahead)
    float4 xr[4];
    {
        const float* x0 = xrow;   // t = 0
        xr[0] = *(const float4*)(x0 + (w    ) * 32 + q * 8);
        xr[1] = *(const float4*)(x0 + (w    ) * 32 + q * 8 + 4);
        xr[2] = *(const float4*)(x0 + (w + 4) * 32 + q * 8);
        xr[3] = *(const float4*)(x0 + (w + 4) * 32 + q * 8 + 4);
    }

    for (int t = 0; t < T_STEPS; ++t) {
        const int p = t & 1, pp = p ^ 1;

        // ---- issue prefetch of x for step t+1 (retires during this step) ----
        float4 xn[4];
        {
            int tn = (t + 1 < T_STEPS) ? t + 1 : t;
            const float* xp = xrow + (size_t)tn * I_DIM;
            xn[0] = *(const float4*)(xp + (w    ) * 32 + q * 8);
            xn[1] = *(const float4*)(xp + (w    ) * 32 + q * 8 + 4);
            xn[2] = *(const float4*)(xp + (w + 4) * 32 + q * 8);
            xn[3] = *(const float4*)(xp + (w + 4) * 32 + q * 8 + 4);
        }

        f32x4 accz = {0,0,0,0}, accr = {0,0,0,0}, acch = {0,0,0,0};

        // x-part MFMAs from registers (no loads, no recurrence dep)
        {
            bf16x8 ax0 = cvt8r(xr[0], xr[1]);
            bf16x8 ax1 = cvt8r(xr[2], xr[3]);
            accz = mfma16(ax0, BZ[0], accz);
            accr = mfma16(ax0, BR[0], accr);
            acch = mfma16(ax0, BH[0], acch);
            accz = mfma16(ax1, BZ[1], accz);
            accr = mfma16(ax1, BR[1], accr);
            acch = mfma16(ax1, BH[1], acch);
        }

        // ---- stage 1: LL-poll h_{t-1} fragment words (tag == t), then MFMA ----
        {
            const u64* hb = hll + ((size_t)((pp * NBT + i) * BT) + ln) * WPB;
            u64 wh[16];
            ll_poll16(hb + (w     ) * 16 + widx,
                      hb + (w +  4) * 16 + widx,
                      hb + (w +  8) * 16 + widx,
                      hb + (w + 12) * 16 + widx,
                      (u32)t, wh);
            #pragma unroll
            for (int s = 0; s < 4; ++s) {
                bf16x8 ah = frag_of(&wh[4 * s]);
                accz = mfma16(ah, BZ[s + 2], accz);
                accr = mfma16(ah, BR[s + 2], accr);
            }
        }

        #pragma unroll
        for (int r4 = 0; r4 < 4; ++r4) {
            red1[0][w][q*4 + r4][ln] = accz[r4];
            red1[1][w][q*4 + r4][ln] = accr[r4];
        }
        __syncthreads();                                         // S1

        // stage-1 epilogue: z, r, publish r*h as LL words (fire-and-forget)
        float zv;
        {
            float pz = red1[0][0][m][c] + red1[0][1][m][c] + red1[0][2][m][c] + red1[0][3][m][c] + bzc;
            float pr = red1[1][0][m][c] + red1[1][1][m][c] + red1[1][2][m][c] + red1[1][3][m][c] + brc;
            zv = 1.0f / (1.0f + __expf(-pz));
            float rv = 1.0f / (1.0f + __expf(-pr));
            unsigned short v16 = __builtin_bit_cast(unsigned short, (__bf16)(rv * hprev));
            unsigned short nb  = (unsigned short)__shfl((int)v16, lane + 1);
            if (!(c & 1)) {
                u64 wrd = (u64)((u32)v16 | ((u32)nb << 16)) | ((u64)(u32)(t + 1) << 32);
                st_u64(rhll + ((size_t)((p * NBT + i) * BT) + m) * WPB + ((cb + c) >> 1), wrd);
            }
        }

        // ---- stage 2: LL-poll r⊙h fragment words (tag == t+1), then MFMA ----
        {
            const u64* rb = rhll + ((size_t)((p * NBT + i) * BT) + ln) * WPB;
            u64 wr_[16];
            ll_poll16(rb + (w     ) * 16 + widx,
                      rb + (w +  4) * 16 + widx,
                      rb + (w +  8) * 16 + widx,
                      rb + (w + 12) * 16 + widx,
                      (u32)(t + 1), wr_);
            #pragma unroll
            for (int s = 0; s < 4; ++s)
                acch = mfma16(frag_of(&wr_[4 * s]), BH[s + 2], acch);
        }

        #pragma unroll
        for (int r4 = 0; r4 < 4; ++r4)
            red2[w][q*4 + r4][ln] = acch[r4];
        __syncthreads();                                         // S2

        // stage-2 epilogue: h~, h_t, publish h as LL words; out[] stores after
        {
            float ph  = red2[0][m][c] + red2[1][m][c] + red2[2][m][c] + red2[3][m][c] + bhc;
            float e2  = __expf(2.0f * ph);
            float htl = (e2 - 1.0f) / (e2 + 1.0f);
            float hn  = (1.0f - zv) * hprev + zv * htl;
            hprev = hn;

            unsigned short v16 = __builtin_bit_cast(unsigned short, (__bf16)hn);
            unsigned short nb  = (unsigned short)__shfl((int)v16, lane + 1);
            if (!(c & 1)) {
                u64 wrd = (u64)((u32)v16 | ((u32)nb << 16)) | ((u64)(u32)(t + 1) << 32);
                st_u64(hll + ((size_t)((p * NBT + i) * BT) + m) * WPB + ((cb + c) >> 1), wrd);
            }

            // off-critical-path output stores
            int bglob = i * BT + m;
            out[((size_t)bglob * T_STEPS + t) * H_DIM + cb + c] = hn;
            if (t == T_STEPS - 1)
                out[(size_t)B_TOT * T_STEPS * H_DIM + (size_t)bglob * H_DIM + cb + c] = hn;
        }

        // roll prefetched x into current
        xr[0] = xn[0]; xr[1] = xn[1]; xr[2] = xn[2]; xr[3] = xn[3];
    }
}

extern "C" void kernel_launch(void* const* d_in, const int* in_sizes, int n_in,
                              void* d_out, int out_size, void* d_ws, size_t ws_size,
                              hipStream_t stream)
{
    const float* xs = (const float*)d_in[0];
    const float* Wz = (const float*)d_in[1];
    const float* bz = (const float*)d_in[2];
    const float* Wr = (const float*)d_in[3];
    const float* br = (const float*)d_in[4];
    const float* Wh = (const float*)d_in[5];
    const float* bh = (const float*)d_in[6];
    float* out = (float*)d_out;

    // ws: hll[2][4][16][256] u64 (256KB) | rhll same (256KB)
    u64* hll  = (u64*)d_ws;
    u64* rhll = hll + LLSZ;

    hipMemsetAsync(d_ws, 0, 2 * LLSZ * sizeof(u64), stream);
    gru_persist<<<dim3(NBT * NCT), dim3(256), 0, stream>>>(
        xs, Wz, bz, Wr, br, Wh, bh, out, hll, rhll);
}

// Round 2
// 7277.385 us; speedup vs baseline: 1.1995x; 1.1995x over previous
//
#include <hip/hip_runtime.h>
#include <cmath>

typedef __bf16 bf16x8 __attribute__((ext_vector_type(8)));
typedef float  f32x4  __attribute__((ext_vector_type(4)));
typedef unsigned int u32;
typedef unsigned long long u64;
typedef u32 u32x4v __attribute__((ext_vector_type(4)));

#define T_STEPS 1024
#define I_DIM   256
#define H_DIM   512
#define B_TOT   64
#define NBT     4     // batch tiles
#define NCT     32    // column tiles
#define BT      16    // batches per tile
#define CT      16    // columns per gate per WG
#define FDOM    64    // ints per flag domain (256B; 32 used, one 128B line)
#define WPB     (H_DIM / 2)            // LL words per batch row (2 bf16 per word)
#define LLSZ    (2 * NBT * BT * WPB)   // u64 words per LL buffer (both parities)

__device__ __forceinline__ f32x4 mfma16(bf16x8 a, bf16x8 b, f32x4 c) {
    return __builtin_amdgcn_mfma_f32_16x16x32_bf16(a, b, c, 0, 0, 0);
}

// two float4 registers -> bf16x8 A-fragment (pure VALU, no loads)
__device__ __forceinline__ bf16x8 cvt8r(float4 a, float4 b) {
    bf16x8 f;
    f[0] = (__bf16)a.x; f[1] = (__bf16)a.y; f[2] = (__bf16)a.z; f[3] = (__bf16)a.w;
    f[4] = (__bf16)b.x; f[5] = (__bf16)b.y; f[6] = (__bf16)b.z; f[7] = (__bf16)b.w;
    return f;
}

// relaxed agent-scope primitives (serviced at the device coherence point)
__device__ __forceinline__ int ld_flag(const int* p) {
    return __hip_atomic_load(p, __ATOMIC_RELAXED, __HIP_MEMORY_SCOPE_AGENT);
}
__device__ __forceinline__ void st_flag(int* p, int v) {
    __hip_atomic_store(p, v, __ATOMIC_RELAXED, __HIP_MEMORY_SCOPE_AGENT);
}
__device__ __forceinline__ u64 ld_u64(const u64* p) {
    return __hip_atomic_load(p, __ATOMIC_RELAXED, __HIP_MEMORY_SCOPE_AGENT);
}
__device__ __forceinline__ void st_u64(u64* p, u64 v) {
    __hip_atomic_store(p, v, __ATOMIC_RELAXED, __HIP_MEMORY_SCOPE_AGENT);
}

// narrow coalesced detect: all 32 per-WG flags of this domain (one 128B line)
// Flags are ADVISORY here — data correctness comes from LL tag validation.
__device__ __forceinline__ void wait32(const int* fdom, int target) {
    const int* p = fdom + (threadIdx.x & 31);
    for (int g = 0; g < (1 << 22); ++g) {
        int v = ld_flag(p);
        if (__ballot(v >= target) == ~0ull) break;
    }
    asm volatile("" ::: "memory");
}

// one-shot load of 16 LL words (4 k-chunks x 4 words) with tag validation.
// Entered only after the flag detect, so retry iterations are rare.
__device__ __forceinline__ void ll_load16(const u64* b0, const u64* b1,
                                          const u64* b2, const u64* b3,
                                          u32 tag, u64* wrd) {
    for (int g = 0; g < (1 << 20); ++g) {
        #pragma unroll
        for (int k = 0; k < 4; ++k) {
            wrd[0  + k] = ld_u64(b0 + k);
            wrd[4  + k] = ld_u64(b1 + k);
            wrd[8  + k] = ld_u64(b2 + k);
            wrd[12 + k] = ld_u64(b3 + k);
        }
        bool ok = true;
        #pragma unroll
        for (int x = 0; x < 16; ++x) ok &= ((u32)(wrd[x] >> 32) == tag);
        if (__ballot(ok) == ~0ull) break;
        __builtin_amdgcn_s_sleep(2);   // backoff: keep rare retries off the LLC
    }
}

// 4 LL words -> bf16x8 A-fragment (low 32 bits of each word = 2 bf16 cols)
__device__ __forceinline__ bf16x8 frag_of(const u64* wrd) {
    u32x4v d;
    d.x = (u32)wrd[0]; d.y = (u32)wrd[1]; d.z = (u32)wrd[2]; d.w = (u32)wrd[3];
    return __builtin_bit_cast(bf16x8, d);
}

// Persistent GRU. Grid: 128 WGs = 4 batch-tiles x 32 column-tiles, 256 thr (4 waves).
// Wave w owns K-steps kk = w + 4*s (s=0..5) of K=768 ([x(256); h(512)]).
// Exchange protocol: LL-tagged data words (fire-and-forget, no drains) +
// narrow coalesced advisory flag line for detection.
__global__ __launch_bounds__(256, 1) void gru_persist(
    const float* __restrict__ xs,
    const float* __restrict__ Wz, const float* __restrict__ bz,
    const float* __restrict__ Wr, const float* __restrict__ br,
    const float* __restrict__ Wh, const float* __restrict__ bh,
    float* __restrict__ out,
    u64* hll, u64* rhll, int* flag_h, int* flag_r)
{
    const int bid  = blockIdx.x;
    const int i    = bid & (NBT - 1);
    const int j    = bid >> 2;
    const int tid  = threadIdx.x;
    const int w    = tid >> 6;
    const int lane = tid & 63;
    const int q    = lane >> 4;
    const int ln   = lane & 15;
    const int cb   = j * CT;

    __shared__ float red1[2][4][16][17];
    __shared__ float red2[4][16][17];

    // ---- stationary weight B-fragments: B[k=q*8+jj][n=ln] per K-step ----
    bf16x8 BZ[6], BR[6], BH[6];
    #pragma unroll
    for (int s = 0; s < 6; ++s) {
        int kk = w + 4 * s;
        int krow = kk * 32 + q * 8;
        bf16x8 fz, fr, fh;
        #pragma unroll
        for (int jj = 0; jj < 8; ++jj) {
            int off = (krow + jj) * H_DIM + cb + ln;
            fz[jj] = (__bf16)Wz[off];
            fr[jj] = (__bf16)Wr[off];
            fh[jj] = (__bf16)Wh[off];
        }
        BZ[s] = fz; BR[s] = fr; BH[s] = fh;
    }

    const int m = tid >> 4;       // epilogue thread -> (batch m, col c)
    const int c = tid & 15;
    const float bzc = bz[cb + c], brc = br[cb + c], bhc = bh[cb + c];
    float hprev = 0.0f;

    const float* xrow = xs + (size_t)(i * BT + ln) * T_STEPS * I_DIM;
    int* fh_dom = flag_h + i * FDOM;
    int* fr_dom = flag_r + i * FDOM;
    int* my_fh  = fh_dom + j;
    int* my_fr  = fr_dom + j;

    const int widx = q * 4;       // word offset within a 32-col k-chunk (16 words)

    // x fragments for current step held in registers (loaded one step ahead)
    float4 xr[4];
    {
        const float* x0 = xrow;   // t = 0
        xr[0] = *(const float4*)(x0 + (w    ) * 32 + q * 8);
        xr[1] = *(const float4*)(x0 + (w    ) * 32 + q * 8 + 4);
        xr[2] = *(const float4*)(x0 + (w + 4) * 32 + q * 8);
        xr[3] = *(const float4*)(x0 + (w + 4) * 32 + q * 8 + 4);
    }

    for (int t = 0; t < T_STEPS; ++t) {
        const int p = t & 1, pp = p ^ 1;

        // ---- issue prefetch of x for step t+1 (retires during this step) ----
        float4 xn[4];
        {
            int tn = (t + 1 < T_STEPS) ? t + 1 : t;
            const float* xp = xrow + (size_t)tn * I_DIM;
            xn[0] = *(const float4*)(xp + (w    ) * 32 + q * 8);
            xn[1] = *(const float4*)(xp + (w    ) * 32 + q * 8 + 4);
            xn[2] = *(const float4*)(xp + (w + 4) * 32 + q * 8);
            xn[3] = *(const float4*)(xp + (w + 4) * 32 + q * 8 + 4);
        }

        f32x4 accz = {0,0,0,0}, accr = {0,0,0,0}, acch = {0,0,0,0};

        // x-part MFMAs from registers (no loads, no recurrence dep)
        {
            bf16x8 ax0 = cvt8r(xr[0], xr[1]);
            bf16x8 ax1 = cvt8r(xr[2], xr[3]);
            accz = mfma16(ax0, BZ[0], accz);
            accr = mfma16(ax0, BR[0], accr);
            acch = mfma16(ax0, BH[0], acch);
            accz = mfma16(ax1, BZ[1], accz);
            accr = mfma16(ax1, BR[1], accr);
            acch = mfma16(ax1, BH[1], acch);
        }

        // ---- stage 1: detect h_{t-1} (narrow flag poll), then one-shot LL load ----
        {
            if (t > 0) wait32(fh_dom, t);
            const u64* hb = hll + ((size_t)((pp * NBT + i) * BT) + ln) * WPB;
            u64 wh[16];
            ll_load16(hb + (w     ) * 16 + widx,
                      hb + (w +  4) * 16 + widx,
                      hb + (w +  8) * 16 + widx,
                      hb + (w + 12) * 16 + widx,
                      (u32)t, wh);
            #pragma unroll
            for (int s = 0; s < 4; ++s) {
                bf16x8 ah = frag_of(&wh[4 * s]);
                accz = mfma16(ah, BZ[s + 2], accz);
                accr = mfma16(ah, BR[s + 2], accr);
            }
        }

        #pragma unroll
        for (int r4 = 0; r4 < 4; ++r4) {
            red1[0][w][q*4 + r4][ln] = accz[r4];
            red1[1][w][q*4 + r4][ln] = accr[r4];
        }
        __syncthreads();                                         // S1

        // stage-1 epilogue: z, r, publish r*h as LL words (fire-and-forget, no drain)
        float zv;
        {
            float pz = red1[0][0][m][c] + red1[0][1][m][c] + red1[0][2][m][c] + red1[0][3][m][c] + bzc;
            float pr = red1[1][0][m][c] + red1[1][1][m][c] + red1[1][2][m][c] + red1[1][3][m][c] + brc;
            zv = 1.0f / (1.0f + __expf(-pz));
            float rv = 1.0f / (1.0f + __expf(-pr));
            unsigned short v16 = __builtin_bit_cast(unsigned short, (__bf16)(rv * hprev));
            unsigned short nb  = (unsigned short)__shfl((int)v16, lane + 1);
            if (!(c & 1)) {
                u64 wrd = (u64)((u32)v16 | ((u32)nb << 16)) | ((u64)(u32)(t + 1) << 32);
                st_u64(rhll + ((size_t)((p * NBT + i) * BT) + m) * WPB + ((cb + c) >> 1), wrd);
            }
            __syncthreads();                                     // S1b: hint quality only
            if (tid == 0) st_flag(my_fr, t + 1);
        }

        // ---- stage 2: detect r⊙h, then one-shot LL load ----
        {
            wait32(fr_dom, t + 1);
            const u64* rb = rhll + ((size_t)((p * NBT + i) * BT) + ln) * WPB;
            u64 wr_[16];
            ll_load16(rb + (w     ) * 16 + widx,
                      rb + (w +  4) * 16 + widx,
                      rb + (w +  8) * 16 + widx,
                      rb + (w + 12) * 16 + widx,
                      (u32)(t + 1), wr_);
            #pragma unroll
            for (int s = 0; s < 4; ++s)
                acch = mfma16(frag_of(&wr_[4 * s]), BH[s + 2], acch);
        }

        #pragma unroll
        for (int r4 = 0; r4 < 4; ++r4)
            red2[w][q*4 + r4][ln] = acch[r4];
        __syncthreads();                                         // S2

        // stage-2 epilogue: h~, h_t, publish h as LL words; out[] stores after flag
        {
            float ph  = red2[0][m][c] + red2[1][m][c] + red2[2][m][c] + red2[3][m][c] + bhc;
            float e2  = __expf(2.0f * ph);
            float htl = (e2 - 1.0f) / (e2 + 1.0f);
            float hn  = (1.0f - zv) * hprev + zv * htl;
            hprev = hn;

            unsigned short v16 = __builtin_bit_cast(unsigned short, (__bf16)hn);
            unsigned short nb  = (unsigned short)__shfl((int)v16, lane + 1);
            if (!(c & 1)) {
                u64 wrd = (u64)((u32)v16 | ((u32)nb << 16)) | ((u64)(u32)(t + 1) << 32);
                st_u64(hll + ((size_t)((p * NBT + i) * BT) + m) * WPB + ((cb + c) >> 1), wrd);
            }
            __syncthreads();                                     // S2b: hint quality only
            if (tid == 0) st_flag(my_fh, t + 1);

            // off-critical-path output stores
            int bglob = i * BT + m;
            out[((size_t)bglob * T_STEPS + t) * H_DIM + cb + c] = hn;
            if (t == T_STEPS - 1)
                out[(size_t)B_TOT * T_STEPS * H_DIM + (size_t)bglob * H_DIM + cb + c] = hn;
        }

        // roll prefetched x into current
        xr[0] = xn[0]; xr[1] = xn[1]; xr[2] = xn[2]; xr[3] = xn[3];
    }
}

extern "C" void kernel_launch(void* const* d_in, const int* in_sizes, int n_in,
                              void* d_out, int out_size, void* d_ws, size_t ws_size,
                              hipStream_t stream)
{
    const float* xs = (const float*)d_in[0];
    const float* Wz = (const float*)d_in[1];
    const float* bz = (const float*)d_in[2];
    const float* Wr = (const float*)d_in[3];
    const float* br = (const float*)d_in[4];
    const float* Wh = (const float*)d_in[5];
    const float* bh = (const float*)d_in[6];
    float* out = (float*)d_out;

    // ws: hll[2][4][16][256] u64 (256KB) | rhll (256KB) |
    //     flag_h[4][64] int (1KB) | flag_r[4][64] int (1KB)
    u64* hll  = (u64*)d_ws;
    u64* rhll = hll + LLSZ;
    int* flag_h = (int*)((char*)d_ws + 2 * LLSZ * sizeof(u64));
    int* flag_r = flag_h + NBT * FDOM;

    hipMemsetAsync(d_ws, 0, 2 * LLSZ * sizeof(u64) + 2 * NBT * FDOM * sizeof(int), stream);
    gru_persist<<<dim3(NBT * NCT), dim3(256), 0, stream>>>(
        xs, Wz, bz, Wr, br, Wh, bh, out, hll, rhll, flag_h, flag_r);
}